// Round 1
// baseline (22.132 us; speedup 1.0000x reference)
//
#include <hip/hip_runtime.h>
#include <math.h>

namespace {

constexpr int kN = 8;
constexpr int kBatch = 500000;
constexpr int kNPairs = 28;  // 8*7/2

// Replicates the torch/jax sample_index ordering:
// gaps 2..7 first (each gap g: j=0..N-1-g), then adjacent pairs (j,j+1) at 21..27.
constexpr int pair_index(int a, int b) {
  const int gap = b - a;
  if (gap == 1) return 21 + a;
  int start = 0;
  for (int g = 2; g < gap; ++g) start += kN - g;
  return start + a;
}

// DFS over increasing element sequences. Each extension adds one chain-pair
// value; every sequence of size >= 3 contributes |x[pair(F,last)] - chain|.
// All indices are compile-time constants -> x[] stays fully in registers.
template <int F, int LAST, int SIZE, int NEXT>
__device__ __forceinline__ void dfs(const float* x, float chain, float& sumAbs) {
  if constexpr (NEXT < kN) {
    const float c2 = chain + x[pair_index(LAST, NEXT)];
    if constexpr (SIZE + 1 >= 3) {
      sumAbs += fabsf(x[pair_index(F, NEXT)] - c2);
    }
    dfs<F, NEXT, SIZE + 1, NEXT + 1>(x, c2, sumAbs);  // extend through NEXT
    dfs<F, LAST, SIZE, NEXT + 1>(x, chain, sumAbs);   // skip NEXT
  }
}

__global__ __launch_bounds__(256) void arc_main(const float* __restrict__ in,
                                                float* __restrict__ partial) {
  const int row = blockIdx.x * 256 + threadIdx.x;
  float v = 0.0f;
  if (row < kBatch) {
    float x[kNPairs];
    const float4* p = reinterpret_cast<const float4*>(in + (size_t)row * kNPairs);
#pragma unroll
    for (int j = 0; j < 7; ++j) {
      const float4 t = p[j];
      x[4 * j + 0] = t.x;
      x[4 * j + 1] = t.y;
      x[4 * j + 2] = t.z;
      x[4 * j + 3] = t.w;
    }
    // A-part: adjacent pairs live at slots 21..27
    float se = 0.0f;
#pragma unroll
    for (int k = 21; k < 28; ++k) se += __expf(-x[k]);
    // B-part: 219 combinatorial residuals via shared-chain DFS (247 adds total)
    float sa = 0.0f;
    dfs<0, 0, 1, 1>(x, 0.0f, sa);
    dfs<1, 1, 1, 2>(x, 0.0f, sa);
    dfs<2, 2, 1, 3>(x, 0.0f, sa);
    dfs<3, 3, 1, 4>(x, 0.0f, sa);
    dfs<4, 4, 1, 5>(x, 0.0f, sa);
    dfs<5, 5, 1, 6>(x, 0.0f, sa);
    v = (0.5f / 7.0f) * se + (0.5f / 219.0f) * sa;
  }
  // wave (64-lane) shuffle reduce, then cross-wave LDS reduce
#pragma unroll
  for (int off = 32; off > 0; off >>= 1) v += __shfl_down(v, off, 64);
  __shared__ float red[4];
  const int lane = threadIdx.x & 63;
  const int wid = threadIdx.x >> 6;
  if (lane == 0) red[wid] = v;
  __syncthreads();
  if (threadIdx.x == 0) {
    partial[blockIdx.x] = red[0] + red[1] + red[2] + red[3];
  }
}

__global__ __launch_bounds__(256) void arc_reduce(const float* __restrict__ partial,
                                                  int n, float* __restrict__ out) {
  double v = 0.0;
  for (int i = threadIdx.x; i < n; i += 256) v += (double)partial[i];
#pragma unroll
  for (int off = 32; off > 0; off >>= 1) v += __shfl_down(v, off, 64);
  __shared__ double red[4];
  const int lane = threadIdx.x & 63;
  const int wid = threadIdx.x >> 6;
  if (lane == 0) red[wid] = v;
  __syncthreads();
  if (threadIdx.x == 0) {
    out[0] = (float)((red[0] + red[1] + red[2] + red[3]) / (double)kBatch);
  }
}

}  // namespace

extern "C" void kernel_launch(void* const* d_in, const int* in_sizes, int n_in,
                              void* d_out, int out_size, void* d_ws, size_t ws_size,
                              hipStream_t stream) {
  const float* in = (const float*)d_in[0];
  float* out = (float*)d_out;
  float* partial = (float*)d_ws;  // needs blocks*4 bytes (~7.8 KB)
  const int blocks = (kBatch + 255) / 256;  // 1954
  arc_main<<<blocks, 256, 0, stream>>>(in, partial);
  arc_reduce<<<1, 256, 0, stream>>>(partial, blocks, out);
}